// Round 3
// baseline (1107.865 us; speedup 1.0000x reference)
//
#include <hip/hip_runtime.h>

#define B_ 16
#define ORDER_ 2
#define N_ 512
#define D_ 128
#define H_ 8

// Pipeline runs in 4 quarters of 8 (b,i) slabs each to keep workspace at
// 4.7 MB (a prior revision used 27 MB and corrupted neighboring allocations
// -> post-timing divergence). h is staged in d_out itself (same layout).

// ---------------------------------------------------------------------------
// Kernel 1: xp[instl, n, col] = sum_c x[bi, n, c] * W[ij, col, c] + pb[ij,col]
// global inst = bi0*2 + instl ; bi = inst>>1 ; ij = (bi&1)*2 + (inst&1)
// 256 thr, 64 rows x 64 cols tile, K-chunks of 32 staged in LDS (pitch 66).
// ---------------------------------------------------------------------------
#define PITCHF 66
__global__ __launch_bounds__(256) void proj_kernel(
    const float* __restrict__ x,
    const float* __restrict__ W,
    const float* __restrict__ pb,
    float* __restrict__ xp,
    int bi0)
{
    __shared__ float xt[32 * PITCHF];   // [c][row]
    __shared__ float wt[32 * PITCHF];   // [c][col]
    const int rt = blockIdx.x;       // 8 row tiles
    const int ct = blockIdx.y;       // 2 col tiles
    const int instl = blockIdx.z;    // 0..15
    const int inst = bi0 * 2 + instl;
    const int j = inst & 1;
    const int bi = inst >> 1;
    const int ij = (bi & 1) * 2 + j;
    const int n0 = rt * 64;
    const int col0 = ct * 64;
    const int t = threadIdx.x;

    const float* xs   = x + ((size_t)bi * N_ + n0) * D_;
    const float* wsrc = W + ((size_t)ij * D_ + col0) * D_;

    const int tc = (t & 15) * 4;   // col base within tile
    const int tr = (t >> 4) * 4;   // row base within tile
    float acc[4][4];
#pragma unroll
    for (int a = 0; a < 4; ++a)
#pragma unroll
        for (int b = 0; b < 4; ++b) acc[a][b] = 0.f;

    for (int c0 = 0; c0 < D_; c0 += 32) {
        for (int idx = t; idx < 64 * 32; idx += 256) {
            const int r = idx >> 5, c = idx & 31;
            xt[c * PITCHF + r] = xs[(size_t)r * D_ + c0 + c];
            wt[c * PITCHF + r] = wsrc[(size_t)r * D_ + c0 + c];  // r = local col
        }
        __syncthreads();
#pragma unroll 8
        for (int c = 0; c < 32; ++c) {
            const float2 xa = *(const float2*)&xt[c * PITCHF + tr];
            const float2 xb = *(const float2*)&xt[c * PITCHF + tr + 2];
            const float2 wa = *(const float2*)&wt[c * PITCHF + tc];
            const float2 wb = *(const float2*)&wt[c * PITCHF + tc + 2];
            const float xf[4] = { xa.x, xa.y, xb.x, xb.y };
            const float wf[4] = { wa.x, wa.y, wb.x, wb.y };
#pragma unroll
            for (int a = 0; a < 4; ++a)
#pragma unroll
                for (int b = 0; b < 4; ++b) acc[a][b] += xf[a] * wf[b];
        }
        __syncthreads();
    }

    float pbv[4];
#pragma unroll
    for (int b = 0; b < 4; ++b) pbv[b] = pb[ij * D_ + col0 + tc + b];
#pragma unroll
    for (int a = 0; a < 4; ++a) {
        float4 o;
        o.x = acc[a][0] + pbv[0];
        o.y = acc[a][1] + pbv[1];
        o.z = acc[a][2] + pbv[2];
        o.w = acc[a][3] + pbv[3];
        *(float4*)&xp[(((size_t)instl * N_) + n0 + tr + a) * D_ + col0 + tc] = o;
    }
}

// ---------------------------------------------------------------------------
// Kernel 2: scores. 256 thr = 2 rows x 128 feats; 16-lane shuffle reduction.
// ---------------------------------------------------------------------------
__global__ __launch_bounds__(256) void score_kernel(
    const float* __restrict__ xp,
    const float* __restrict__ att_src,
    const float* __restrict__ att_dst,
    float* __restrict__ ssrc,
    float* __restrict__ sdst,
    int bi0)
{
    const int instl = blockIdx.y;
    const int inst = bi0 * 2 + instl;
    const int ij = ((inst >> 1) & 1) * 2 + (inst & 1);
    const int n = blockIdx.x * 2 + (threadIdx.x >> 7);
    const int d = threadIdx.x & 127;
    const float v = xp[(((size_t)instl * N_) + n) * D_ + d];
    float ss = v * att_src[ij * D_ + d];
    float sd = v * att_dst[ij * D_ + d];
#pragma unroll
    for (int off = 1; off < 16; off <<= 1) {
        ss += __shfl_xor(ss, off, 64);
        sd += __shfl_xor(sd, off, 64);
    }
    if ((d & 15) == 0) {
        const int h = d >> 4;
        ssrc[(((size_t)instl * N_) + n) * H_ + h] = ss;
        sdst[(((size_t)instl * N_) + n) * H_ + h] = sd;
    }
}

// ---------------------------------------------------------------------------
// Kernel 3: attention; both convs fused. Block = (bi_local, 16-dst tile).
// Masked entries contribute w = exp(0) = 1 (ref: mask->0 logit BEFORE leaky,
// softmax over ALL 512 src). h = sum_j [(sum_s w*xh)/Z + xp_self + bias],
// written into d_out (h layout == out layout).
// ---------------------------------------------------------------------------
__global__ __launch_bounds__(256) void attn_kernel(
    const float* __restrict__ xp,
    const int* __restrict__ A,
    const float* __restrict__ ssrc,
    const float* __restrict__ sdst,
    const float* __restrict__ bias,
    float* __restrict__ hout,
    int bi0)
{
    __shared__ float ss_l[N_ * H_];      // 16 KB
    __shared__ float sd_l[16 * H_];
    __shared__ float w_l[16 * 16 * H_];  // 8 KB  [s_local][dl][h]
    __shared__ float zbuf[256];
    __shared__ float zl[16 * H_];

    const int d0 = blockIdx.x * 16;
    const int bil = blockIdx.y;          // 0..7
    const int bi = bi0 + bil;
    const int i_ = bi & 1;
    const int t = threadIdx.x;

    // phase-1 mapping: fixed (dl,h), even/odd src
    const int p1_dl = (t >> 3) & 15;
    const int p1_h  = t & 7;
    const int sodd  = t >> 7;
    // phase-2 mapping: fixed (dl,h), 8 consecutive feats
    const int p2_dl = t >> 4;
    const int p2_h  = (t >> 1) & 7;
    const int p2_f  = p2_h * 16 + (t & 1) * 8;

    const int* Ab = A + (size_t)bi * N_ * N_;

    float hacc[8];
#pragma unroll
    for (int m = 0; m < 8; ++m) hacc[m] = 0.f;

    for (int j = 0; j < 2; ++j) {
        const int instl = bil * 2 + j;
        const int ij = i_ * 2 + j;
        const float* ssp = ssrc + (size_t)instl * N_ * H_;
        for (int idx = t; idx < N_ * H_; idx += 256) ss_l[idx] = ssp[idx];
        if (t < 128) sd_l[t] = sdst[(size_t)instl * N_ * H_ + d0 * H_ + t];
        __syncthreads();

        const float sdv = sd_l[p1_dl * H_ + p1_h];
        float zpart = 0.f;
        float acc[8];
#pragma unroll
        for (int m = 0; m < 8; ++m) acc[m] = 0.f;
        const float* xh = xp + (size_t)instl * N_ * D_;

        for (int s0 = 0; s0 < N_; s0 += 16) {
#pragma unroll
            for (int k = 0; k < 8; ++k) {
                const int sl = sodd + 2 * k;
                const int s = s0 + sl;
                const int a = Ab[(size_t)s * N_ + d0 + p1_dl];
                const bool edge = (j == 0) ? (a == 2 || a == 4) : (a == 3 || a == 4);
                float w = 1.0f;
                if (edge) {
                    const float z = ss_l[s * H_ + p1_h] + sdv;
                    w = __expf(z >= 0.f ? z : 0.2f * z);
                }
                w_l[sl * 128 + p1_dl * H_ + p1_h] = w;
                zpart += w;
            }
            __syncthreads();
#pragma unroll 4
            for (int sl = 0; sl < 16; ++sl) {
                const float* xr = xh + (size_t)(s0 + sl) * D_ + p2_f;
                const float4 x0 = *(const float4*)xr;
                const float4 x1 = *(const float4*)(xr + 4);
                const float wv = w_l[sl * 128 + p2_dl * H_ + p2_h];
                acc[0] += wv * x0.x; acc[1] += wv * x0.y;
                acc[2] += wv * x0.z; acc[3] += wv * x0.w;
                acc[4] += wv * x1.x; acc[5] += wv * x1.y;
                acc[6] += wv * x1.z; acc[7] += wv * x1.w;
            }
            __syncthreads();
        }

        zbuf[t] = zpart;
        __syncthreads();
        if (t < 128) zl[t] = zbuf[t] + zbuf[t + 128];
        __syncthreads();

        const float Zinv = 1.0f / zl[p2_dl * H_ + p2_h];
        const float* xpself = xh + (size_t)(d0 + p2_dl) * D_ + p2_f;
        const float* bp = bias + ij * D_ + p2_f;
#pragma unroll
        for (int m = 0; m < 8; ++m)
            hacc[m] += acc[m] * Zinv + xpself[m] + bp[m];
        __syncthreads();   // before next j restages ss_l/sd_l
    }

    float* hp = hout + (((size_t)bi * N_) + d0 + p2_dl) * D_ + p2_f;
    float4 o0 = { hacc[0], hacc[1], hacc[2], hacc[3] };
    float4 o1 = { hacc[4], hacc[5], hacc[6], hacc[7] };
    *(float4*)hp = o0;
    *(float4*)(hp + 4) = o1;
}

// ---------------------------------------------------------------------------
// Kernel 4: in-place on d_out. Each thread owns one float4 slice for BOTH i
// values of one b (no cross-block read/write overlap -> race-free in place):
// out[b,0] = 1.5*h0 + 0.5*h1 ; out[b,1] = 1.5*h1 + 0.5*h0.
// ---------------------------------------------------------------------------
__global__ __launch_bounds__(256) void combine_kernel(float* __restrict__ h)
{
    const int idx = blockIdx.x * 256 + threadIdx.x;   // 0..262143 (float4 units)
    const int b = idx >> 14;                          // 16384 float4 per i-slab
    const int r = idx & 16383;
    float4* p0 = (float4*)h + (size_t)b * 32768 + r;
    float4* p1 = p0 + 16384;
    const float4 a = *p0;
    const float4 o = *p1;
    float4 r0, r1;
    r0.x = 1.5f * a.x + 0.5f * o.x;  r1.x = 1.5f * o.x + 0.5f * a.x;
    r0.y = 1.5f * a.y + 0.5f * o.y;  r1.y = 1.5f * o.y + 0.5f * a.y;
    r0.z = 1.5f * a.z + 0.5f * o.z;  r1.z = 1.5f * o.z + 0.5f * a.z;
    r0.w = 1.5f * a.w + 0.5f * o.w;  r1.w = 1.5f * o.w + 0.5f * a.w;
    *p0 = r0;
    *p1 = r1;
}

extern "C" void kernel_launch(void* const* d_in, const int* in_sizes, int n_in,
                              void* d_out, int out_size, void* d_ws, size_t ws_size,
                              hipStream_t stream)
{
    const float* x   = (const float*)d_in[0];
    const int*   A   = (const int*)d_in[1];
    const float* W   = (const float*)d_in[2];
    const float* pb  = (const float*)d_in[3];
    const float* as_ = (const float*)d_in[4];
    const float* ad_ = (const float*)d_in[5];
    const float* bs  = (const float*)d_in[6];

    // Workspace (per-quarter, reused): 16*512*128 + 2*16*512*8 floats = 4.7 MB
    float* xp   = (float*)d_ws;
    float* ssrc = xp + (size_t)16 * 512 * 128;
    float* sdst = ssrc + (size_t)16 * 512 * 8;
    float* h    = (float*)d_out;   // h staged in d_out (same layout as out)

    for (int q = 0; q < 4; ++q) {
        const int bi0 = q * 8;
        proj_kernel<<<dim3(8, 2, 16), 256, 0, stream>>>(x, W, pb, xp, bi0);
        score_kernel<<<dim3(256, 16), 256, 0, stream>>>(xp, as_, ad_, ssrc, sdst, bi0);
        attn_kernel<<<dim3(32, 8), 256, 0, stream>>>(xp, A, ssrc, sdst, bs, h, bi0);
    }
    combine_kernel<<<1024, 256, 0, stream>>>(h);
}

// Round 4
// 332.579 us; speedup vs baseline: 3.3311x; 3.3311x over previous
//
#include <hip/hip_runtime.h>

#define B_ 16
#define ORDER_ 2
#define N_ 512
#define D_ 128
#define H_ 8

// ws layout: xp as bf16 for ALL 64 instances = 64*512*128*2 B = 8,388,608 B
// (== out bytes; 27.3 MB of ws previously corrupted neighboring buffers, and
// 4.7 MB was safe — this sits at the plausible ws_size == out_nbytes bound).
// h is staged in d_out (same layout as out); combine mixes in place.

__device__ __forceinline__ unsigned short f2bf(float f) {
    unsigned int u = __float_as_uint(f);
    u += 0x7fffu + ((u >> 16) & 1u);
    return (unsigned short)(u >> 16);
}
__device__ __forceinline__ float bflo(unsigned int u) { return __uint_as_float(u << 16); }
__device__ __forceinline__ float bfhi(unsigned int u) { return __uint_as_float(u & 0xffff0000u); }

// ---------------------------------------------------------------------------
// Kernel 1: xp[inst, n, col] = sum_c x[bi,n,c] * W[ij,col,c] + pb[ij,col],
// stored bf16 (RNE). 256 thr, 64x64 tile, K-chunks of 32 in LDS (pitch 66).
// ---------------------------------------------------------------------------
#define PITCHF 66
__global__ __launch_bounds__(256) void proj_kernel(
    const float* __restrict__ x,
    const float* __restrict__ W,
    const float* __restrict__ pb,
    unsigned short* __restrict__ xp)
{
    __shared__ float xt[32 * PITCHF];   // [c][row]
    __shared__ float wt[32 * PITCHF];   // [c][col]
    const int rt = blockIdx.x;       // 8 row tiles
    const int ct = blockIdx.y;       // 2 col tiles
    const int inst = blockIdx.z;     // 64
    const int j = inst & 1;
    const int bi = inst >> 1;
    const int ij = (bi & 1) * 2 + j;
    const int n0 = rt * 64;
    const int col0 = ct * 64;
    const int t = threadIdx.x;

    const float* xs   = x + ((size_t)bi * N_ + n0) * D_;
    const float* wsrc = W + ((size_t)ij * D_ + col0) * D_;

    const int tc = (t & 15) * 4;
    const int tr = (t >> 4) * 4;
    float acc[4][4];
#pragma unroll
    for (int a = 0; a < 4; ++a)
#pragma unroll
        for (int b = 0; b < 4; ++b) acc[a][b] = 0.f;

    for (int c0 = 0; c0 < D_; c0 += 32) {
        for (int idx = t; idx < 64 * 32; idx += 256) {
            const int r = idx >> 5, c = idx & 31;
            xt[c * PITCHF + r] = xs[(size_t)r * D_ + c0 + c];
            wt[c * PITCHF + r] = wsrc[(size_t)r * D_ + c0 + c];
        }
        __syncthreads();
#pragma unroll 8
        for (int c = 0; c < 32; ++c) {
            const float2 xa = *(const float2*)&xt[c * PITCHF + tr];
            const float2 xb = *(const float2*)&xt[c * PITCHF + tr + 2];
            const float2 wa = *(const float2*)&wt[c * PITCHF + tc];
            const float2 wb = *(const float2*)&wt[c * PITCHF + tc + 2];
            const float xf[4] = { xa.x, xa.y, xb.x, xb.y };
            const float wf[4] = { wa.x, wa.y, wb.x, wb.y };
#pragma unroll
            for (int a = 0; a < 4; ++a)
#pragma unroll
                for (int b = 0; b < 4; ++b) acc[a][b] += xf[a] * wf[b];
        }
        __syncthreads();
    }

    float pbv[4];
#pragma unroll
    for (int b = 0; b < 4; ++b) pbv[b] = pb[ij * D_ + col0 + tc + b];
#pragma unroll
    for (int a = 0; a < 4; ++a) {
        const unsigned int p0 = f2bf(acc[a][0] + pbv[0]) | ((unsigned int)f2bf(acc[a][1] + pbv[1]) << 16);
        const unsigned int p1 = f2bf(acc[a][2] + pbv[2]) | ((unsigned int)f2bf(acc[a][3] + pbv[3]) << 16);
        uint2 pk = { p0, p1 };
        *(uint2*)&xp[(((size_t)inst * N_) + n0 + tr + a) * D_ + col0 + tc] = pk;
    }
}

// ---------------------------------------------------------------------------
// Kernel 2: attention. Block = (bi, 32-dst tile), 256 thr = 32 dst x 8 heads;
// thread owns one (dst,h) with all 16 feats -> complete per-thread softmax
// denominator, no reductions. Scores computed inline from staged xh chunks.
// Masked entries contribute w = exp(0) = 1 (ref: mask->0 logit BEFORE leaky,
// softmax over ALL 512 src). h = sum_j [(sum_s w*xh)/Z + xp_self + bias].
// ---------------------------------------------------------------------------
#define XPITCH 132
__global__ __launch_bounds__(256) void attn_kernel(
    const unsigned short* __restrict__ xp,
    const int* __restrict__ A,
    const float* __restrict__ att_src,
    const float* __restrict__ att_dst,
    const float* __restrict__ bias,
    float* __restrict__ hout)
{
    __shared__ float xh_l[32 * XPITCH];  // 16.9 KB, fp32 chunk of xh
    __shared__ int   A_l[32 * 32];       // 4 KB
    __shared__ float ss_l[32 * 8];       // 1 KB
    __shared__ float as_l[128];
    __shared__ float ad_l[128];

    const int tile = blockIdx.x;   // 0..15
    const int bi   = blockIdx.y;   // 0..31
    const int i_ = bi & 1;
    const int d0 = tile * 32;
    const int t = threadIdx.x;
    const int dst = t >> 3;        // 0..31 (also reused as sl for staging/ss)
    const int h   = t & 7;
    const int dg  = d0 + dst;

    const int* Ab = A + (size_t)bi * N_ * N_;

    float hacc[16];
#pragma unroll
    for (int m = 0; m < 16; ++m) hacc[m] = 0.f;

#pragma unroll
    for (int j = 0; j < 2; ++j) {
        const int inst = bi * 2 + j;
        const int ij = i_ * 2 + j;
        const unsigned short* xpi = xp + (size_t)inst * N_ * D_;

        __syncthreads();            // previous j's consumers done
        if (t < 128) {
            as_l[t] = att_src[ij * D_ + t];
            ad_l[t] = att_dst[ij * D_ + t];
        }
        __syncthreads();

        // sd for this thread's (dst, h)
        float sd = 0.f;
        {
            const unsigned short* xr = xpi + (size_t)dg * D_ + h * 16;
            const uint4 b0 = *(const uint4*)xr;
            const uint4 b1 = *(const uint4*)(xr + 8);
            const float xv[16] = {
                bflo(b0.x), bfhi(b0.x), bflo(b0.y), bfhi(b0.y),
                bflo(b0.z), bfhi(b0.z), bflo(b0.w), bfhi(b0.w),
                bflo(b1.x), bfhi(b1.x), bflo(b1.y), bfhi(b1.y),
                bflo(b1.z), bfhi(b1.z), bflo(b1.w), bfhi(b1.w) };
#pragma unroll
            for (int k = 0; k < 16; ++k) sd += xv[k] * ad_l[h * 16 + k];
        }

        float acc[16];
#pragma unroll
        for (int m = 0; m < 16; ++m) acc[m] = 0.f;
        float zsum = 0.f;

        for (int s0 = 0; s0 < N_; s0 += 32) {
            __syncthreads();   // previous chunk fully consumed
            // stage A tile: thread t -> row t>>3, cols (t&7)*4..+4
            {
                const int4 av = *(const int4*)&Ab[(size_t)(s0 + (t >> 3)) * N_ + d0 + (t & 7) * 4];
                *(int4*)&A_l[(t >> 3) * 32 + (t & 7) * 4] = av;
            }
            // stage xh chunk (bf16 -> fp32): thread t -> row t>>3, f0=(t&7)*16
            {
                const unsigned short* xr = xpi + (size_t)(s0 + (t >> 3)) * D_ + (t & 7) * 16;
                const uint4 b0 = *(const uint4*)xr;
                const uint4 b1 = *(const uint4*)(xr + 8);
                float* wp = &xh_l[(t >> 3) * XPITCH + (t & 7) * 16];
                float4 f0 = { bflo(b0.x), bfhi(b0.x), bflo(b0.y), bfhi(b0.y) };
                float4 f1 = { bflo(b0.z), bfhi(b0.z), bflo(b0.w), bfhi(b0.w) };
                float4 f2 = { bflo(b1.x), bfhi(b1.x), bflo(b1.y), bfhi(b1.y) };
                float4 f3 = { bflo(b1.z), bfhi(b1.z), bflo(b1.w), bfhi(b1.w) };
                *(float4*)(wp)      = f0;
                *(float4*)(wp + 4)  = f1;
                *(float4*)(wp + 8)  = f2;
                *(float4*)(wp + 12) = f3;
            }
            __syncthreads();
            // ss for (sl = dst, h)
            {
                float ssv = 0.f;
                const float* xrow = &xh_l[dst * XPITCH + h * 16];
#pragma unroll
                for (int k = 0; k < 16; ++k) ssv += xrow[k] * as_l[h * 16 + k];
                ss_l[dst * 8 + h] = ssv;
            }
            __syncthreads();
            // main: 32 src per chunk
#pragma unroll 4
            for (int sl = 0; sl < 32; ++sl) {
                const int a = A_l[sl * 32 + dst];
                const bool edge = (a == 4) || (a == (j ? 3 : 2));
                const float z0 = ss_l[sl * 8 + h] + sd;
                const float zr = z0 >= 0.f ? z0 : 0.2f * z0;
                const float w = edge ? __expf(zr) : 1.0f;
                zsum += w;
                const float* xr = &xh_l[sl * XPITCH + h * 16];
                const float4 x0 = *(const float4*)xr;
                const float4 x1 = *(const float4*)(xr + 4);
                const float4 x2 = *(const float4*)(xr + 8);
                const float4 x3 = *(const float4*)(xr + 12);
                acc[0]  += w * x0.x; acc[1]  += w * x0.y; acc[2]  += w * x0.z; acc[3]  += w * x0.w;
                acc[4]  += w * x1.x; acc[5]  += w * x1.y; acc[6]  += w * x1.z; acc[7]  += w * x1.w;
                acc[8]  += w * x2.x; acc[9]  += w * x2.y; acc[10] += w * x2.z; acc[11] += w * x2.w;
                acc[12] += w * x3.x; acc[13] += w * x3.y; acc[14] += w * x3.z; acc[15] += w * x3.w;
            }
        }

        // epilogue for this conv
        const float Zinv = 1.0f / zsum;
        {
            const unsigned short* xr = xpi + (size_t)dg * D_ + h * 16;
            const uint4 b0 = *(const uint4*)xr;
            const uint4 b1 = *(const uint4*)(xr + 8);
            const float xs[16] = {
                bflo(b0.x), bfhi(b0.x), bflo(b0.y), bfhi(b0.y),
                bflo(b0.z), bfhi(b0.z), bflo(b0.w), bfhi(b0.w),
                bflo(b1.x), bfhi(b1.x), bflo(b1.y), bfhi(b1.y),
                bflo(b1.z), bfhi(b1.z), bflo(b1.w), bfhi(b1.w) };
            const float* bp = bias + ij * D_ + h * 16;
#pragma unroll
            for (int k = 0; k < 16; ++k)
                hacc[k] += acc[k] * Zinv + xs[k] + bp[k];
        }
    }

    float* hp = hout + (((size_t)bi * N_) + dg) * D_ + h * 16;
    *(float4*)hp        = *(float4*)&hacc[0];
    *(float4*)(hp + 4)  = *(float4*)&hacc[4];
    *(float4*)(hp + 8)  = *(float4*)&hacc[8];
    *(float4*)(hp + 12) = *(float4*)&hacc[12];
}

// ---------------------------------------------------------------------------
// Kernel 3: in-place on d_out. Thread owns one float4 slice for BOTH i of one
// b (no cross-block overlap): out0 = 1.5 h0 + 0.5 h1 ; out1 = 1.5 h1 + 0.5 h0.
// ---------------------------------------------------------------------------
__global__ __launch_bounds__(256) void combine_kernel(float* __restrict__ h)
{
    const int idx = blockIdx.x * 256 + threadIdx.x;   // float4 units
    const int b = idx >> 14;
    const int r = idx & 16383;
    float4* p0 = (float4*)h + (size_t)b * 32768 + r;
    float4* p1 = p0 + 16384;
    const float4 a = *p0;
    const float4 o = *p1;
    float4 r0, r1;
    r0.x = 1.5f * a.x + 0.5f * o.x;  r1.x = 1.5f * o.x + 0.5f * a.x;
    r0.y = 1.5f * a.y + 0.5f * o.y;  r1.y = 1.5f * o.y + 0.5f * a.y;
    r0.z = 1.5f * a.z + 0.5f * o.z;  r1.z = 1.5f * o.z + 0.5f * a.z;
    r0.w = 1.5f * a.w + 0.5f * o.w;  r1.w = 1.5f * o.w + 0.5f * a.w;
    *p0 = r0;
    *p1 = r1;
}

extern "C" void kernel_launch(void* const* d_in, const int* in_sizes, int n_in,
                              void* d_out, int out_size, void* d_ws, size_t ws_size,
                              hipStream_t stream)
{
    const float* x   = (const float*)d_in[0];
    const int*   A   = (const int*)d_in[1];
    const float* W   = (const float*)d_in[2];
    const float* pb  = (const float*)d_in[3];
    const float* as_ = (const float*)d_in[4];
    const float* ad_ = (const float*)d_in[5];
    const float* bs  = (const float*)d_in[6];

    unsigned short* xp = (unsigned short*)d_ws;   // 8,388,608 B
    float* h = (float*)d_out;

    proj_kernel<<<dim3(8, 2, 64), 256, 0, stream>>>(x, W, pb, xp);
    attn_kernel<<<dim3(16, 32), 256, 0, stream>>>(xp, A, as_, ad_, bs, h);
    combine_kernel<<<1024, 256, 0, stream>>>(h);
}

// Round 5
// 302.335 us; speedup vs baseline: 3.6644x; 1.1000x over previous
//
#include <hip/hip_runtime.h>

#define B_ 16
#define ORDER_ 2
#define N_ 512
#define D_ 128
#define H_ 8

// ws: xp bf16 for all 64 instances = 8,388,608 B. h staged in d_out.

__device__ __forceinline__ unsigned short f2bf(float f) {
    unsigned int u = __float_as_uint(f);
    u += 0x7fffu + ((u >> 16) & 1u);
    return (unsigned short)(u >> 16);
}
__device__ __forceinline__ float bflo(unsigned int u) { return __uint_as_float(u << 16); }
__device__ __forceinline__ float bfhi(unsigned int u) { return __uint_as_float(u & 0xffff0000u); }

// ---------------------------------------------------------------------------
// Kernel 1: xp[inst,n,col] = sum_c x[bi,n,c]*W[ij,col,c] + pb[ij,col], bf16 out.
// ---------------------------------------------------------------------------
#define PITCHF 66
__global__ __launch_bounds__(256) void proj_kernel(
    const float* __restrict__ x,
    const float* __restrict__ W,
    const float* __restrict__ pb,
    unsigned short* __restrict__ xp)
{
    __shared__ float xt[32 * PITCHF];
    __shared__ float wt[32 * PITCHF];
    const int rt = blockIdx.x;
    const int ct = blockIdx.y;
    const int inst = blockIdx.z;
    const int j = inst & 1;
    const int bi = inst >> 1;
    const int ij = (bi & 1) * 2 + j;
    const int n0 = rt * 64;
    const int col0 = ct * 64;
    const int t = threadIdx.x;

    const float* xs   = x + ((size_t)bi * N_ + n0) * D_;
    const float* wsrc = W + ((size_t)ij * D_ + col0) * D_;

    const int tc = (t & 15) * 4;
    const int tr = (t >> 4) * 4;
    float acc[4][4];
#pragma unroll
    for (int a = 0; a < 4; ++a)
#pragma unroll
        for (int b = 0; b < 4; ++b) acc[a][b] = 0.f;

    for (int c0 = 0; c0 < D_; c0 += 32) {
        for (int idx = t; idx < 64 * 32; idx += 256) {
            const int r = idx >> 5, c = idx & 31;
            xt[c * PITCHF + r] = xs[(size_t)r * D_ + c0 + c];
            wt[c * PITCHF + r] = wsrc[(size_t)r * D_ + c0 + c];
        }
        __syncthreads();
#pragma unroll 8
        for (int c = 0; c < 32; ++c) {
            const float2 xa = *(const float2*)&xt[c * PITCHF + tr];
            const float2 xb = *(const float2*)&xt[c * PITCHF + tr + 2];
            const float2 wa = *(const float2*)&wt[c * PITCHF + tc];
            const float2 wb = *(const float2*)&wt[c * PITCHF + tc + 2];
            const float xf[4] = { xa.x, xa.y, xb.x, xb.y };
            const float wf[4] = { wa.x, wa.y, wb.x, wb.y };
#pragma unroll
            for (int a = 0; a < 4; ++a)
#pragma unroll
                for (int b = 0; b < 4; ++b) acc[a][b] += xf[a] * wf[b];
        }
        __syncthreads();
    }

    float pbv[4];
#pragma unroll
    for (int b = 0; b < 4; ++b) pbv[b] = pb[ij * D_ + col0 + tc + b];
#pragma unroll
    for (int a = 0; a < 4; ++a) {
        const unsigned int p0 = f2bf(acc[a][0] + pbv[0]) | ((unsigned int)f2bf(acc[a][1] + pbv[1]) << 16);
        const unsigned int p1 = f2bf(acc[a][2] + pbv[2]) | ((unsigned int)f2bf(acc[a][3] + pbv[3]) << 16);
        uint2 pk = { p0, p1 };
        *(uint2*)&xp[(((size_t)inst * N_) + n0 + tr + a) * D_ + col0 + tc] = pk;
    }
}

// ---------------------------------------------------------------------------
// Kernel 2: attention. Block = (bi, 32-dst tile). Two thread mappings:
//   w-gen: (dst = t&31, h = t>>5) computes w for 16 src/chunk + Z in regs.
//   PV:    (dstq = t>>5, h = (t>>2)&7, fq = t&3): 4 dst x 4 feats.
// ss for all 512 src computed once per conv into LDS. xh staged as raw bf16
// (8 B/lane reads, <=2-way banks); w fp32 with 36-float h-stride (<=2-way).
// Masked entries: w = exp(0) = 1; softmax over all 512 src.
// ---------------------------------------------------------------------------
#define WL_PITCH 288
__global__ __launch_bounds__(256) void attn_kernel(
    const unsigned short* __restrict__ xp,
    const int* __restrict__ A,
    const float* __restrict__ att_src,
    const float* __restrict__ att_dst,
    const float* __restrict__ bias,
    float* __restrict__ hout)
{
    __shared__ unsigned short xh_l[16 * 128];   // 4 KB raw bf16 chunk
    __shared__ int   A_l[16 * 32];              // 2 KB
    __shared__ float w_l[16 * WL_PITCH];        // 18.4 KB [sl][h*36+dst]
    __shared__ float ss_all[N_ * 8];            // 16 KB [s][h]
    __shared__ float z_l[8 * 32];               // 1 KB [h][dst]
    __shared__ float as_l[128];
    __shared__ float ad_l[128];

    const int tile = blockIdx.x;   // 0..15
    const int bi   = blockIdx.y;   // 0..31
    const int i_ = bi & 1;
    const int d0 = tile * 32;
    const int t = threadIdx.x;

    const int wg_dst = t & 31;       // w-gen mapping
    const int wg_h   = t >> 5;
    const int dstq = t >> 5;         // PV mapping
    const int pv_h = (t >> 2) & 7;
    const int fq   = t & 3;

    const int* Ab = A + (size_t)bi * N_ * N_;

    float hacc[16];
#pragma unroll
    for (int m = 0; m < 16; ++m) hacc[m] = 0.f;

    for (int j = 0; j < 2; ++j) {
        const int inst = bi * 2 + j;
        const int ij = i_ * 2 + j;
        const unsigned short* xpi = xp + (size_t)inst * N_ * D_;
        const int aedge = j ? 3 : 2;

        __syncthreads();             // prev conv consumers done
        if (t < 128) {
            as_l[t] = att_src[ij * D_ + t];
            ad_l[t] = att_dst[ij * D_ + t];
        }
        __syncthreads();

        // ss for all 512 src: thread = (h = t&7, sbase = t>>3), 16 rows each
        {
            const int sh = t & 7;
            const int sbase = t >> 3;
#pragma unroll 4
            for (int m = 0; m < 16; ++m) {
                const int s = sbase + 32 * m;
                const unsigned short* xr = xpi + (size_t)s * D_ + sh * 16;
                const uint4 b0 = *(const uint4*)xr;
                const uint4 b1 = *(const uint4*)(xr + 8);
                const float xv[16] = {
                    bflo(b0.x), bfhi(b0.x), bflo(b0.y), bfhi(b0.y),
                    bflo(b0.z), bfhi(b0.z), bflo(b0.w), bfhi(b0.w),
                    bflo(b1.x), bfhi(b1.x), bflo(b1.y), bfhi(b1.y),
                    bflo(b1.z), bfhi(b1.z), bflo(b1.w), bfhi(b1.w) };
                float ssv = 0.f;
#pragma unroll
                for (int k = 0; k < 16; ++k) ssv += xv[k] * as_l[sh * 16 + k];
                ss_all[s * 8 + sh] = ssv;
            }
        }
        // sd for this w-gen thread's (d0+wg_dst, wg_h)
        float sd = 0.f;
        {
            const unsigned short* xr = xpi + (size_t)(d0 + wg_dst) * D_ + wg_h * 16;
            const uint4 b0 = *(const uint4*)xr;
            const uint4 b1 = *(const uint4*)(xr + 8);
            const float xv[16] = {
                bflo(b0.x), bfhi(b0.x), bflo(b0.y), bfhi(b0.y),
                bflo(b0.z), bfhi(b0.z), bflo(b0.w), bfhi(b0.w),
                bflo(b1.x), bfhi(b1.x), bflo(b1.y), bfhi(b1.y),
                bflo(b1.z), bfhi(b1.z), bflo(b1.w), bfhi(b1.w) };
#pragma unroll
            for (int k = 0; k < 16; ++k) sd += xv[k] * ad_l[wg_h * 16 + k];
        }

        float acc[16];
#pragma unroll
        for (int m = 0; m < 16; ++m) acc[m] = 0.f;
        float zacc = 0.f;

        for (int s0 = 0; s0 < N_; s0 += 16) {
            __syncthreads();   // prev chunk consumed (also covers ss_all ready)
            if (t < 128) {     // A tile: row t>>3, cols (t&7)*4
                const int4 av = *(const int4*)&Ab[(size_t)(s0 + (t >> 3)) * N_ + d0 + (t & 7) * 4];
                *(int4*)&A_l[(t >> 3) * 32 + (t & 7) * 4] = av;
            }
            {                  // xh chunk raw bf16 copy: row t>>4, 8 bf16 at (t&15)*8
                const unsigned short* xr = xpi + (size_t)(s0 + (t >> 4)) * D_ + (t & 15) * 8;
                *(uint4*)&xh_l[(t >> 4) * 128 + (t & 15) * 8] = *(const uint4*)xr;
            }
            __syncthreads();
            // w-gen: 16 sl for (wg_dst, wg_h)
#pragma unroll
            for (int sl = 0; sl < 16; ++sl) {
                const int a = A_l[sl * 32 + wg_dst];
                const bool edge = (a == 4) || (a == aedge);
                const float z0 = ss_all[(s0 + sl) * 8 + wg_h] + sd;
                const float zr = z0 >= 0.f ? z0 : 0.2f * z0;
                const float w = edge ? __expf(zr) : 1.0f;
                w_l[sl * WL_PITCH + wg_h * 36 + wg_dst] = w;
                zacc += w;
            }
            __syncthreads();
            // PV: 16 sl, 4 dst x 4 feats
#pragma unroll
            for (int sl = 0; sl < 16; ++sl) {
                const float4 w4 = *(const float4*)&w_l[sl * WL_PITCH + pv_h * 36 + dstq * 4];
                const uint2 xb = *(const uint2*)&xh_l[sl * 128 + pv_h * 16 + fq * 4];
                const float x0 = bflo(xb.x), x1 = bfhi(xb.x);
                const float x2 = bflo(xb.y), x3 = bfhi(xb.y);
                acc[0]  += w4.x * x0; acc[1]  += w4.x * x1; acc[2]  += w4.x * x2; acc[3]  += w4.x * x3;
                acc[4]  += w4.y * x0; acc[5]  += w4.y * x1; acc[6]  += w4.y * x2; acc[7]  += w4.y * x3;
                acc[8]  += w4.z * x0; acc[9]  += w4.z * x1; acc[10] += w4.z * x2; acc[11] += w4.z * x3;
                acc[12] += w4.w * x0; acc[13] += w4.w * x1; acc[14] += w4.w * x2; acc[15] += w4.w * x3;
            }
        }

        __syncthreads();
        z_l[wg_h * 32 + wg_dst] = zacc;
        __syncthreads();

        // epilogue: hacc += acc/Z + xp_self + bias
        const float* bp = bias + ij * D_ + pv_h * 16 + fq * 4;
        const float b0v = bp[0], b1v = bp[1], b2v = bp[2], b3v = bp[3];
#pragma unroll
        for (int dd = 0; dd < 4; ++dd) {
            const int dst = d0 + dstq * 4 + dd;
            const float Zi = 1.0f / z_l[pv_h * 32 + dstq * 4 + dd];
            const unsigned short* xr = xpi + (size_t)dst * D_ + pv_h * 16 + fq * 4;
            const uint2 xb = *(const uint2*)xr;
            hacc[dd * 4 + 0] += acc[dd * 4 + 0] * Zi + bflo(xb.x) + b0v;
            hacc[dd * 4 + 1] += acc[dd * 4 + 1] * Zi + bfhi(xb.x) + b1v;
            hacc[dd * 4 + 2] += acc[dd * 4 + 2] * Zi + bflo(xb.y) + b2v;
            hacc[dd * 4 + 3] += acc[dd * 4 + 3] * Zi + bfhi(xb.y) + b3v;
        }
    }

#pragma unroll
    for (int dd = 0; dd < 4; ++dd) {
        float* hp = hout + (((size_t)bi * N_) + d0 + dstq * 4 + dd) * D_ + pv_h * 16 + fq * 4;
        float4 o = { hacc[dd * 4 + 0], hacc[dd * 4 + 1], hacc[dd * 4 + 2], hacc[dd * 4 + 3] };
        *(float4*)hp = o;
    }
}

// ---------------------------------------------------------------------------
// Kernel 3: in-place mix on d_out (thread owns both i slices of one b).
// ---------------------------------------------------------------------------
__global__ __launch_bounds__(256) void combine_kernel(float* __restrict__ h)
{
    const int idx = blockIdx.x * 256 + threadIdx.x;
    const int b = idx >> 14;
    const int r = idx & 16383;
    float4* p0 = (float4*)h + (size_t)b * 32768 + r;
    float4* p1 = p0 + 16384;
    const float4 a = *p0;
    const float4 o = *p1;
    float4 r0, r1;
    r0.x = 1.5f * a.x + 0.5f * o.x;  r1.x = 1.5f * o.x + 0.5f * a.x;
    r0.y = 1.5f * a.y + 0.5f * o.y;  r1.y = 1.5f * o.y + 0.5f * a.y;
    r0.z = 1.5f * a.z + 0.5f * o.z;  r1.z = 1.5f * o.z + 0.5f * a.z;
    r0.w = 1.5f * a.w + 0.5f * o.w;  r1.w = 1.5f * o.w + 0.5f * a.w;
    *p0 = r0;
    *p1 = r1;
}

extern "C" void kernel_launch(void* const* d_in, const int* in_sizes, int n_in,
                              void* d_out, int out_size, void* d_ws, size_t ws_size,
                              hipStream_t stream)
{
    const float* x   = (const float*)d_in[0];
    const int*   A   = (const int*)d_in[1];
    const float* W   = (const float*)d_in[2];
    const float* pb  = (const float*)d_in[3];
    const float* as_ = (const float*)d_in[4];
    const float* ad_ = (const float*)d_in[5];
    const float* bs  = (const float*)d_in[6];

    unsigned short* xp = (unsigned short*)d_ws;   // 8,388,608 B
    float* h = (float*)d_out;

    proj_kernel<<<dim3(8, 2, 64), 256, 0, stream>>>(x, W, pb, xp);
    attn_kernel<<<dim3(16, 32), 256, 0, stream>>>(xp, A, as_, ad_, bs, h);
    combine_kernel<<<1024, 256, 0, stream>>>(h);
}